// Round 3
// baseline (413.667 us; speedup 1.0000x reference)
//
#include <hip/hip_runtime.h>

// Element-wise: y = min(((x+1)*0.75)^2, 10.0f), fp32 in/out, 8192*8192 elems.
// Memory-bound streaming map. float4 (native clang vector) loads, grid-stride,
// nontemporal loads/stores (no reuse -> don't pollute L2/L3).

typedef float f4 __attribute__((ext_vector_type(4)));

__global__ __launch_bounds__(256) void ew_kernel(const f4* __restrict__ x,
                                                 f4* __restrict__ out,
                                                 int n4) {
    int stride = gridDim.x * blockDim.x;
    for (int i = blockIdx.x * blockDim.x + threadIdx.x; i < n4; i += stride) {
        f4 v = __builtin_nontemporal_load(&x[i]);
        f4 t = (v + 1.0f) * 0.75f;
        f4 r = t * t;
        r.x = fminf(r.x, 10.0f);
        r.y = fminf(r.y, 10.0f);
        r.z = fminf(r.z, 10.0f);
        r.w = fminf(r.w, 10.0f);
        __builtin_nontemporal_store(r, &out[i]);
    }
}

extern "C" void kernel_launch(void* const* d_in, const int* in_sizes, int n_in,
                              void* d_out, int out_size, void* d_ws, size_t ws_size,
                              hipStream_t stream) {
    const float* x = (const float*)d_in[0];
    float* out = (float*)d_out;
    int n = in_sizes[0];          // 8192*8192 = 67108864, divisible by 4
    int n4 = n / 4;               // 16777216 float4s
    int block = 256;
    int grid = 8192;              // 256 CUs x 32 blocks; 8 f4/thread grid-stride
    ew_kernel<<<grid, block, 0, stream>>>((const f4*)x, (f4*)out, n4);
}